// Round 12
// baseline (191.256 us; speedup 1.0000x reference)
//
#include <hip/hip_runtime.h>

// HamiltonianMetric: y[b] = u^T u, u = scatter(tanh(MLP(x))).
// R12: 16 batches/block, 80KB LDS -> 2 blocks/CU so one block's stage-4
// (HBM-write-heavy) overlaps the other's stage-3 (L2-read-heavy). R11's
// phases were barrier-serialized at 1 block/CU: sum 45us/gen -> max().
// W3q 1KB-burst loads + asm vmcnt pipeline + fused gram all unchanged.

typedef __bf16 bf16_t;
typedef bf16_t bf16x8 __attribute__((ext_vector_type(8)));
typedef float  f32x4  __attribute__((ext_vector_type(4)));

#define MFMA16(a, b, c) __builtin_amdgcn_mfma_f32_16x16x32_bf16((a), (b), (c), 0, 0, 0)

constexpr int SLOT  = 4608;   // bytes per uT slot (XOR-swizzled)
constexpr int H2OFF = 73728;  // 16*SLOT; h2s at [73728,81920)

__device__ __forceinline__ float fast_tanh(float x) {
  float cx = fminf(fmaxf(x, -30.0f), 30.0f);
  float t  = __expf(2.0f * cx);
  return (t - 1.0f) * __builtin_amdgcn_rcpf(t + 1.0f);
}

__device__ __forceinline__ bf16x8 zsel(bf16x8 f, bool keep) {
  union { bf16x8 v; unsigned int u[4]; } x;
  x.v = f;
  unsigned m = keep ? 0xFFFFFFFFu : 0u;
#pragma unroll
  for (int p = 0; p < 4; ++p) x.u[p] &= m;
  return x.v;
}

// padded position p -> (j, k): row j has j+1 valid entries, padded to 8-mult
__device__ __forceinline__ void decode_p(int p, int& j, int& k) {
  int cc = p >> 3, e = p & 7;
  int b = 0;
  while (b < 7 && cc >= 4 * (b + 1) * (b + 2)) ++b;
  int rl  = b + 1;
  int rem = cc - 4 * b * (b + 1);
  j = 8 * b + rem / rl;
  k = (rem % rl) * 8 + e;
}

// ws: [0,16384) W1t[256n][64k] | [16384,81920) W2t[256n][256k] |
//     [81920,671744) W3q tile-major: [144 t][8 kk][64 lane][8 e]
//     byte 1343488: b3p[2304] f32 (permuted triangle bias, 0 in padding)
__global__ void prep_kernel(const float* __restrict__ W1, const float* __restrict__ W2,
                            const float* __restrict__ W3, const float* __restrict__ b3,
                            char* __restrict__ wsb) {
  int tid = blockIdx.x * 512 + threadIdx.x;
  bf16_t* ws = (bf16_t*)wsb;
  if (tid < 16384) {
    int n = tid >> 6, k = tid & 63;
    ws[tid] = (bf16_t)W1[k * 256 + n];
  } else if (tid < 81920) {
    int m = tid - 16384;
    int n = m >> 8, k = m & 255;
    ws[tid] = (bf16_t)W2[k * 256 + n];
  } else if (tid < 671744) {
    int m = tid - 81920;
    int t  = m >> 12;
    int r  = m & 4095;
    int kk = r >> 9;
    int g  = (r >> 7) & 3;
    int c  = (r >> 3) & 15;
    int e  = r & 7;
    int p  = t * 16 + c;          // triangle position
    int k  = kk * 32 + g * 8 + e; // H-dim column
    int j, kd;
    decode_p(p, j, kd);
    float v = 0.f;
    if (kd <= j) {
      int n_ref = (kd == j) ? j : (64 + kd * 63 - (kd * (kd - 1)) / 2 + j - kd - 1);
      v = W3[k * 2080 + n_ref];
    }
    ws[tid] = (bf16_t)v;
  } else if (tid < 674048) {
    int p = tid - 671744;
    int j, kd;
    decode_p(p, j, kd);
    float v = 0.f;
    if (kd <= j) {
      int n_ref = (kd == j) ? j : (64 + kd * 63 - (kd * (kd - 1)) / 2 + j - kd - 1);
      v = b3[n_ref];
    }
    ((float*)(wsb + 1343488))[p] = v;
  }
}

// ---------------- fused kernel: 16 batches/block, 8 waves, 2 blocks/CU ----------------
__global__ void __launch_bounds__(512, 4)
hm_kernel(const float* __restrict__ x, const float* __restrict__ b1,
          const float* __restrict__ b2, const char* __restrict__ wsb,
          float* __restrict__ out) {
  extern __shared__ char smem[];  // 81920 B
  const int tid  = threadIdx.x;
  const int w    = tid >> 6;    // wave 0..7
  const int lane = tid & 63;
  const int g    = lane >> 4;
  const int c    = lane & 15;
  const int blk  = blockIdx.x;

  const bf16_t* W1t = (const bf16_t*)wsb;
  const bf16_t* W2t = W1t + 16384;
  const bf16_t* W3q = W1t + 81920;
  const float*  b3p = (const float*)(wsb + 1343488);

  char* xs  = smem;          // [16][64]  bf16, swz (stage 1; inside slot area)
  char* h1s = smem + 8192;   // [16][256] bf16, swz (stages 1-2; inside slot area)
  char* h2s = smem + H2OFF;  // [16][256] bf16, swz (outside slot area)

  // ---- load x: 16 rows x 64 f32 -> bf16 LDS ----
  if (tid < 256) {
    f32x4 v = *(const f32x4*)(x + (size_t)blk * 1024 + tid * 4);
    int row = tid >> 4, col = (tid & 15) * 4;
    union { bf16_t b[4]; unsigned long long u; } pk;
    pk.b[0] = (bf16_t)v[0]; pk.b[1] = (bf16_t)v[1];
    pk.b[2] = (bf16_t)v[2]; pk.b[3] = (bf16_t)v[3];
    *(unsigned long long*)(xs + ((row * 128 + col * 2) ^ ((row & 7) << 4))) = pk.u;
  }
  __syncthreads();

  // ---- stage 1: h1 = tanh(x @ W1 + b1) ----
  {
    bf16x8 a0 = *(const bf16x8*)(xs + ((c * 128 + g * 16) ^ ((c & 7) << 4)));
    bf16x8 a1 = *(const bf16x8*)(xs + ((c * 128 + 64 + g * 16) ^ ((c & 7) << 4)));
#pragma unroll
    for (int ni = 0; ni < 2; ++ni) {
      int n = (w * 2 + ni) * 16 + c;
      bf16x8 bw0 = *(const bf16x8*)(W1t + n * 64 + g * 8);
      bf16x8 bw1 = *(const bf16x8*)(W1t + n * 64 + 32 + g * 8);
      f32x4 acc = {0.f, 0.f, 0.f, 0.f};
      acc = MFMA16(a0, bw0, acc);
      acc = MFMA16(a1, bw1, acc);
      float bias = b1[n];
#pragma unroll
      for (int r = 0; r < 4; ++r) {
        int row = g * 4 + r;
        float v = fast_tanh(acc[r] + bias);
        *(bf16_t*)(h1s + ((row * 512 + n * 2) ^ ((row & 7) << 4))) = (bf16_t)v;
      }
    }
  }
  __syncthreads();

  // ---- stage 2: h2 = tanh(h1 @ W2 + b2) ----
#pragma unroll
  for (int ni = 0; ni < 2; ++ni) {
    int n = (w * 2 + ni) * 16 + c;
    f32x4 acc0 = {0.f, 0.f, 0.f, 0.f}, acc1 = {0.f, 0.f, 0.f, 0.f};
#pragma unroll
    for (int kk = 0; kk < 8; kk += 2) {
      bf16x8 a0 = *(const bf16x8*)(h1s + ((c * 512 + kk * 64 + g * 16) ^ ((c & 7) << 4)));
      bf16x8 a1 = *(const bf16x8*)(h1s + ((c * 512 + (kk + 1) * 64 + g * 16) ^ ((c & 7) << 4)));
      bf16x8 bw0 = *(const bf16x8*)(W2t + n * 256 + kk * 32 + g * 8);
      bf16x8 bw1 = *(const bf16x8*)(W2t + n * 256 + (kk + 1) * 32 + g * 8);
      acc0 = MFMA16(a0, bw0, acc0);
      acc1 = MFMA16(a1, bw1, acc1);
    }
    f32x4 acc = acc0 + acc1;
    float bias = b2[n];
#pragma unroll
    for (int r = 0; r < 4; ++r) {
      int row = g * 4 + r;
      float v = fast_tanh(acc[r] + bias);
      *(bf16_t*)(h2s + ((row * 512 + n * 2) ^ ((row & 7) << 4))) = (bf16_t)v;
    }
  }
  __syncthreads();

  // ---- stage 3: t = tanh(h2 @ W3 + b3) -> 16 uT slots (XOR-swizzled) ----
  // h2s is outside the slot arena; A-frags read once, no barrier needed inside.
  {
    bf16x8 a0 = *(const bf16x8*)(h2s + ((c * 512 + 0 * 64 + g * 16) ^ ((c & 7) << 4)));
    bf16x8 a1 = *(const bf16x8*)(h2s + ((c * 512 + 1 * 64 + g * 16) ^ ((c & 7) << 4)));
    bf16x8 a2 = *(const bf16x8*)(h2s + ((c * 512 + 2 * 64 + g * 16) ^ ((c & 7) << 4)));
    bf16x8 a3 = *(const bf16x8*)(h2s + ((c * 512 + 3 * 64 + g * 16) ^ ((c & 7) << 4)));
    bf16x8 a4 = *(const bf16x8*)(h2s + ((c * 512 + 4 * 64 + g * 16) ^ ((c & 7) << 4)));
    bf16x8 a5 = *(const bf16x8*)(h2s + ((c * 512 + 5 * 64 + g * 16) ^ ((c & 7) << 4)));
    bf16x8 a6 = *(const bf16x8*)(h2s + ((c * 512 + 6 * 64 + g * 16) ^ ((c & 7) << 4)));
    bf16x8 a7 = *(const bf16x8*)(h2s + ((c * 512 + 7 * 64 + g * 16) ^ ((c & 7) << 4)));

    char* tw = smem + (g * 4) * SLOT;   // slots g*4+r
    const int swz = (g & 7) << 4;       // slot-group XOR swizzle (m>>2 = g)

    bf16x8 A0, A1, A2, A3, A4, A5, A6, A7; float Ab;
    bf16x8 B0, B1, B2, B3, B4, B5, B6, B7; float Bb;

#define ISSUE_T(S, TI)                                                              \
  do {                                                                              \
    int t_ = w + (TI) * 8;                                                          \
    const bf16_t* np_ = W3q + t_ * 4096 + lane * 8;                                 \
    asm volatile("global_load_dwordx4 %0, %1, off" : "=v"(S##0) : "v"(np_));            \
    asm volatile("global_load_dwordx4 %0, %1, off" : "=v"(S##1) : "v"(np_ + 512));      \
    asm volatile("global_load_dwordx4 %0, %1, off" : "=v"(S##2) : "v"(np_ + 1024));     \
    asm volatile("global_load_dwordx4 %0, %1, off" : "=v"(S##3) : "v"(np_ + 1536));     \
    asm volatile("global_load_dwordx4 %0, %1, off" : "=v"(S##4) : "v"(np_ + 2048));     \
    asm volatile("global_load_dwordx4 %0, %1, off" : "=v"(S##5) : "v"(np_ + 2560));     \
    asm volatile("global_load_dwordx4 %0, %1, off" : "=v"(S##6) : "v"(np_ + 3072));     \
    asm volatile("global_load_dwordx4 %0, %1, off" : "=v"(S##7) : "v"(np_ + 3584));     \
    asm volatile("global_load_dword %0, %1, off"   : "=v"(S##b) : "v"(b3p + t_ * 16 + c)); \
  } while (0)

#define WAIT_N(N)                                          \
  do {                                                     \
    asm volatile("s_waitcnt vmcnt(" #N ")" ::: "memory");  \
    __builtin_amdgcn_sched_barrier(0);                     \
  } while (0)

#define COMP_T(S, TI)                                                    \
  do {                                                                   \
    f32x4 acc0 = {S##b, S##b, S##b, S##b};                               \
    f32x4 acc1 = {0.f, 0.f, 0.f, 0.f};                                   \
    acc0 = MFMA16(a0, S##0, acc0); acc1 = MFMA16(a1, S##1, acc1);        \
    acc0 = MFMA16(a2, S##2, acc0); acc1 = MFMA16(a3, S##3, acc1);        \
    acc0 = MFMA16(a4, S##4, acc0); acc1 = MFMA16(a5, S##5, acc1);        \
    acc0 = MFMA16(a6, S##6, acc0); acc1 = MFMA16(a7, S##7, acc1);        \
    f32x4 accs = acc0 + acc1;                                            \
    int p_ = (w + (TI) * 8) * 16 + c;                                    \
    _Pragma("unroll")                                                    \
    for (int r_ = 0; r_ < 4; ++r_) {                                     \
      float v_ = fast_tanh(accs[r_]);                                    \
      *(bf16_t*)(tw + r_ * SLOT + ((p_ * 2) ^ swz)) = (bf16_t)v_;        \
    }                                                                    \
  } while (0)

    ISSUE_T(A, 0);
#pragma unroll 1
    for (int pr = 0; pr < 8; ++pr) {
      ISSUE_T(B, 2 * pr + 1);
      WAIT_N(9);
      COMP_T(A, 2 * pr);
      ISSUE_T(A, 2 * pr + 2);
      WAIT_N(9);
      COMP_T(B, 2 * pr + 1);
    }
    ISSUE_T(B, 17);
    WAIT_N(9);
    COMP_T(A, 16);
    WAIT_N(0);
    COMP_T(B, 17);

#undef ISSUE_T
#undef WAIT_N
#undef COMP_T
  }
  __syncthreads();

  // ---- stage 4 (fused Gram): wave w -> batches 2w, 2w+1, from LDS ----
#pragma unroll
  for (int bi = 0; bi < 2; ++bi) {
    int m = w * 2 + bi;
    char* slot = smem + m * SLOT;
    const int sw = ((m >> 2) & 7) << 4;

    bf16x8 f0, f1, f2, f3, f2b, f3b;
#pragma unroll
    for (int ti = 0; ti < 4; ++ti) {
      int j = ti * 16 + c;
      int Q = j >> 3, s = j & 7;
      int ro = 16 * (4 * Q * (Q + 1) + s * (Q + 1));
      bf16x8 fa = *(const bf16x8*)(slot + ((ro + g * 16) ^ sw));
      if (ti == 0) f0 = zsel(fa, g * 8 <= j);
      if (ti == 1) f1 = zsel(fa, g * 8 <= j);
      if (ti == 2) f2 = fa;
      if (ti == 3) f3 = fa;
      if (ti >= 2) {
        bf16x8 fb = *(const bf16x8*)(slot + ((ro + 64 + g * 16) ^ sw));
        fb = zsel(fb, 32 + g * 8 <= j);
        if (ti == 2) f2b = fb;
        else         f3b = fb;
      }
    }

    bf16x8 fA[4] = {f0, f1, f2, f3};
    f32x4 acc[4][4];
#pragma unroll
    for (int ti = 0; ti < 4; ++ti)
#pragma unroll
      for (int tj = 0; tj < 4; ++tj) {
        f32x4 z = {0.f, 0.f, 0.f, 0.f};
        acc[ti][tj] = MFMA16(fA[ti], fA[tj], z);
      }
    acc[2][2] = MFMA16(f2b, f2b, acc[2][2]);
    acc[2][3] = MFMA16(f2b, f3b, acc[2][3]);
    acc[3][2] = MFMA16(f3b, f2b, acc[3][2]);
    acc[3][3] = MFMA16(f3b, f3b, acc[3][3]);

    // slot is dead now -> reuse as 4KB y-staging; 1KB-contiguous stores
    float* yb = out + (size_t)(blk * 16 + m) * 4096;
#pragma unroll
    for (int ti = 0; ti < 4; ++ti) {
#pragma unroll
      for (int tj = 0; tj < 4; ++tj)
#pragma unroll
        for (int r = 0; r < 4; ++r)
          *(float*)(slot + (g * 4 + r) * 256 + (tj * 16 + c) * 4) = acc[ti][tj][r];
#pragma unroll
      for (int ii = 0; ii < 4; ++ii) {
        f32x4 v = *(const f32x4*)(slot + ii * 1024 + lane * 16);
        *(f32x4*)(yb + ti * 1024 + ii * 256 + lane * 4) = v;
      }
    }
  }
}

extern "C" void kernel_launch(void* const* d_in, const int* in_sizes, int n_in,
                              void* d_out, int out_size, void* d_ws, size_t ws_size,
                              hipStream_t stream) {
  (void)in_sizes; (void)n_in; (void)out_size; (void)ws_size;
  const float* x  = (const float*)d_in[0];
  const float* W1 = (const float*)d_in[1];
  const float* b1 = (const float*)d_in[2];
  const float* W2 = (const float*)d_in[3];
  const float* b2 = (const float*)d_in[4];
  const float* W3 = (const float*)d_in[5];
  const float* b3 = (const float*)d_in[6];
  char* wsb = (char*)d_ws;   // needs 1,352,704 B
  float* out = (float*)d_out;

  prep_kernel<<<1317, 512, 0, stream>>>(W1, W2, W3, b3, wsb);

  hipFuncSetAttribute((const void*)hm_kernel,
                      hipFuncAttributeMaxDynamicSharedMemorySize, 81920);
  hm_kernel<<<2048, 512, 81920, stream>>>(x, b1, b2, wsb, out);
}

// Round 14
// 182.633 us; speedup vs baseline: 1.0472x; 1.0472x over previous
//
#include <hip/hip_runtime.h>

// HamiltonianMetric: y[b] = u^T u, u = scatter(tanh(MLP(x))).
// R14 = R11 (last-known-good, passed post-timing) + two low-risk changes:
//  1) stage-3 prefetch deepened 2->3 buffers (vmcnt(18)): covers ~720cy of L2
//     latency at 2 waves/SIMD (R11's 2-deep left an exposed gap per tile).
//  2) staged y stores made nontemporal (full-line) so the 512MB y stream
//     doesn't evict W3q from L2 between block generations.
// R13's 16-wave rework raced post-timing and showed no perf upside; reverted.

typedef __bf16 bf16_t;
typedef bf16_t bf16x8 __attribute__((ext_vector_type(8)));
typedef float  f32x4  __attribute__((ext_vector_type(4)));

#define MFMA16(a, b, c) __builtin_amdgcn_mfma_f32_16x16x32_bf16((a), (b), (c), 0, 0, 0)

constexpr int SLOT  = 4608;   // bytes per uT slot (XOR-swizzled)
constexpr int H2OFF = 147456; // 32*SLOT; h2s at [147456,163840)

__device__ __forceinline__ float fast_tanh(float x) {
  float cx = fminf(fmaxf(x, -30.0f), 30.0f);
  float t  = __expf(2.0f * cx);
  return (t - 1.0f) * __builtin_amdgcn_rcpf(t + 1.0f);
}

__device__ __forceinline__ bf16x8 zsel(bf16x8 f, bool keep) {
  union { bf16x8 v; unsigned int u[4]; } x;
  x.v = f;
  unsigned m = keep ? 0xFFFFFFFFu : 0u;
#pragma unroll
  for (int p = 0; p < 4; ++p) x.u[p] &= m;
  return x.v;
}

// padded position p -> (j, k): row j has j+1 valid entries, padded to 8-mult
__device__ __forceinline__ void decode_p(int p, int& j, int& k) {
  int cc = p >> 3, e = p & 7;
  int b = 0;
  while (b < 7 && cc >= 4 * (b + 1) * (b + 2)) ++b;
  int rl  = b + 1;
  int rem = cc - 4 * b * (b + 1);
  j = 8 * b + rem / rl;
  k = (rem % rl) * 8 + e;
}

// ws: [0,16384) W1t[256n][64k] | [16384,81920) W2t[256n][256k] |
//     [81920,671744) W3q tile-major: [144 t][8 kk][64 lane][8 e]
//     byte 1343488: b3p[2304] f32 (permuted triangle bias, 0 in padding)
__global__ void prep_kernel(const float* __restrict__ W1, const float* __restrict__ W2,
                            const float* __restrict__ W3, const float* __restrict__ b3,
                            char* __restrict__ wsb) {
  int tid = blockIdx.x * 512 + threadIdx.x;
  bf16_t* ws = (bf16_t*)wsb;
  if (tid < 16384) {
    int n = tid >> 6, k = tid & 63;
    ws[tid] = (bf16_t)W1[k * 256 + n];
  } else if (tid < 81920) {
    int m = tid - 16384;
    int n = m >> 8, k = m & 255;
    ws[tid] = (bf16_t)W2[k * 256 + n];
  } else if (tid < 671744) {
    int m = tid - 81920;
    int t  = m >> 12;
    int r  = m & 4095;
    int kk = r >> 9;
    int g  = (r >> 7) & 3;
    int c  = (r >> 3) & 15;
    int e  = r & 7;
    int p  = t * 16 + c;          // triangle position
    int k  = kk * 32 + g * 8 + e; // H-dim column
    int j, kd;
    decode_p(p, j, kd);
    float v = 0.f;
    if (kd <= j) {
      int n_ref = (kd == j) ? j : (64 + kd * 63 - (kd * (kd - 1)) / 2 + j - kd - 1);
      v = W3[k * 2080 + n_ref];
    }
    ws[tid] = (bf16_t)v;
  } else if (tid < 674048) {
    int p = tid - 671744;
    int j, kd;
    decode_p(p, j, kd);
    float v = 0.f;
    if (kd <= j) {
      int n_ref = (kd == j) ? j : (64 + kd * 63 - (kd * (kd - 1)) / 2 + j - kd - 1);
      v = b3[n_ref];
    }
    ((float*)(wsb + 1343488))[p] = v;
  }
}

// ---------------- fused kernel: 32 batches/block, 8 waves ----------------
__global__ void __launch_bounds__(512, 2)
hm_kernel(const float* __restrict__ x, const float* __restrict__ b1,
          const float* __restrict__ b2, const char* __restrict__ wsb,
          float* __restrict__ out) {
  extern __shared__ char smem[];  // 163840 B
  const int tid  = threadIdx.x;
  const int w    = tid >> 6;    // wave 0..7
  const int lane = tid & 63;
  const int g    = lane >> 4;
  const int c    = lane & 15;
  const int blk  = blockIdx.x;

  const bf16_t* W1t = (const bf16_t*)wsb;
  const bf16_t* W2t = W1t + 16384;
  const bf16_t* W3q = W1t + 81920;
  const float*  b3p = (const float*)(wsb + 1343488);

  char* xs  = smem;          // [32][64]  bf16, swz (stage 1 only)
  char* h1s = smem + 8192;   // [32][256] bf16, swz (stages 1-2)
  char* h2s = smem + H2OFF;  // [32][256] bf16, swz (stages 2-3)

  // ---- load x: 32 rows x 64 f32 -> bf16 LDS (512 thr x 4 floats) ----
  {
    f32x4 v = *(const f32x4*)(x + (size_t)blk * 2048 + tid * 4);
    int row = tid >> 4, col = (tid & 15) * 4;
    union { bf16_t b[4]; unsigned long long u; } pk;
    pk.b[0] = (bf16_t)v[0]; pk.b[1] = (bf16_t)v[1];
    pk.b[2] = (bf16_t)v[2]; pk.b[3] = (bf16_t)v[3];
    *(unsigned long long*)(xs + ((row * 128 + col * 2) ^ ((row & 7) << 4))) = pk.u;
  }
  __syncthreads();

  // ---- stage 1: h1 = tanh(x @ W1 + b1); wave covers both mt halves ----
#pragma unroll
  for (int mt = 0; mt < 2; ++mt) {
    int arow = mt * 16 + c;
    bf16x8 a0 = *(const bf16x8*)(xs + ((arow * 128 + g * 16) ^ ((arow & 7) << 4)));
    bf16x8 a1 = *(const bf16x8*)(xs + ((arow * 128 + 64 + g * 16) ^ ((arow & 7) << 4)));
#pragma unroll
    for (int ni = 0; ni < 2; ++ni) {
      int n = (w * 2 + ni) * 16 + c;
      bf16x8 bw0 = *(const bf16x8*)(W1t + n * 64 + g * 8);
      bf16x8 bw1 = *(const bf16x8*)(W1t + n * 64 + 32 + g * 8);
      f32x4 acc = {0.f, 0.f, 0.f, 0.f};
      acc = MFMA16(a0, bw0, acc);
      acc = MFMA16(a1, bw1, acc);
      float bias = b1[n];
#pragma unroll
      for (int r = 0; r < 4; ++r) {
        int row = mt * 16 + g * 4 + r;
        float v = fast_tanh(acc[r] + bias);
        *(bf16_t*)(h1s + ((row * 512 + n * 2) ^ ((row & 7) << 4))) = (bf16_t)v;
      }
    }
  }
  __syncthreads();

  // ---- stage 2: h2 = tanh(h1 @ W2 + b2); both halves per wave ----
#pragma unroll
  for (int mt = 0; mt < 2; ++mt) {
    int arow = mt * 16 + c;
#pragma unroll
    for (int ni = 0; ni < 2; ++ni) {
      int n = (w * 2 + ni) * 16 + c;
      f32x4 acc0 = {0.f, 0.f, 0.f, 0.f}, acc1 = {0.f, 0.f, 0.f, 0.f};
#pragma unroll
      for (int kk = 0; kk < 8; kk += 2) {
        bf16x8 a0 = *(const bf16x8*)(h1s + ((arow * 512 + kk * 64 + g * 16) ^ ((arow & 7) << 4)));
        bf16x8 a1 = *(const bf16x8*)(h1s + ((arow * 512 + (kk + 1) * 64 + g * 16) ^ ((arow & 7) << 4)));
        bf16x8 bw0 = *(const bf16x8*)(W2t + n * 256 + kk * 32 + g * 8);
        bf16x8 bw1 = *(const bf16x8*)(W2t + n * 256 + (kk + 1) * 32 + g * 8);
        acc0 = MFMA16(a0, bw0, acc0);
        acc1 = MFMA16(a1, bw1, acc1);
      }
      f32x4 acc = acc0 + acc1;
      float bias = b2[n];
#pragma unroll
      for (int r = 0; r < 4; ++r) {
        int row = mt * 16 + g * 4 + r;
        float v = fast_tanh(acc[r] + bias);
        *(bf16_t*)(h2s + ((row * 512 + n * 2) ^ ((row & 7) << 4))) = (bf16_t)v;
      }
    }
  }
  __syncthreads();

  // ---- stage 3: t = tanh(h2 @ W3 + b3); ONE B-tile load serves BOTH halves ----
  // 3-deep prefetch (A/B/C), WAIT(18) = two tiles in flight over each compute.
  {
    int arowL = c, arowH = 16 + c;
    bf16x8 aL0 = *(const bf16x8*)(h2s + ((arowL * 512 + 0 * 64 + g * 16) ^ ((arowL & 7) << 4)));
    bf16x8 aL1 = *(const bf16x8*)(h2s + ((arowL * 512 + 1 * 64 + g * 16) ^ ((arowL & 7) << 4)));
    bf16x8 aL2 = *(const bf16x8*)(h2s + ((arowL * 512 + 2 * 64 + g * 16) ^ ((arowL & 7) << 4)));
    bf16x8 aL3 = *(const bf16x8*)(h2s + ((arowL * 512 + 3 * 64 + g * 16) ^ ((arowL & 7) << 4)));
    bf16x8 aL4 = *(const bf16x8*)(h2s + ((arowL * 512 + 4 * 64 + g * 16) ^ ((arowL & 7) << 4)));
    bf16x8 aL5 = *(const bf16x8*)(h2s + ((arowL * 512 + 5 * 64 + g * 16) ^ ((arowL & 7) << 4)));
    bf16x8 aL6 = *(const bf16x8*)(h2s + ((arowL * 512 + 6 * 64 + g * 16) ^ ((arowL & 7) << 4)));
    bf16x8 aL7 = *(const bf16x8*)(h2s + ((arowL * 512 + 7 * 64 + g * 16) ^ ((arowL & 7) << 4)));
    bf16x8 aH0 = *(const bf16x8*)(h2s + ((arowH * 512 + 0 * 64 + g * 16) ^ ((arowH & 7) << 4)));
    bf16x8 aH1 = *(const bf16x8*)(h2s + ((arowH * 512 + 1 * 64 + g * 16) ^ ((arowH & 7) << 4)));
    bf16x8 aH2 = *(const bf16x8*)(h2s + ((arowH * 512 + 2 * 64 + g * 16) ^ ((arowH & 7) << 4)));
    bf16x8 aH3 = *(const bf16x8*)(h2s + ((arowH * 512 + 3 * 64 + g * 16) ^ ((arowH & 7) << 4)));
    bf16x8 aH4 = *(const bf16x8*)(h2s + ((arowH * 512 + 4 * 64 + g * 16) ^ ((arowH & 7) << 4)));
    bf16x8 aH5 = *(const bf16x8*)(h2s + ((arowH * 512 + 5 * 64 + g * 16) ^ ((arowH & 7) << 4)));
    bf16x8 aH6 = *(const bf16x8*)(h2s + ((arowH * 512 + 6 * 64 + g * 16) ^ ((arowH & 7) << 4)));
    bf16x8 aH7 = *(const bf16x8*)(h2s + ((arowH * 512 + 7 * 64 + g * 16) ^ ((arowH & 7) << 4)));

    char* twL = smem + (g * 4) * SLOT;          // slots g*4+r       (mt=0)
    char* twH = smem + (16 + g * 4) * SLOT;     // slots 16+g*4+r    (mt=1)
    const int swzL = (g & 7) << 4;
    const int swzH = ((4 + g) & 7) << 4;

    bf16x8 A0, A1, A2, A3, A4, A5, A6, A7; float Ab;
    bf16x8 B0, B1, B2, B3, B4, B5, B6, B7; float Bb;
    bf16x8 C0, C1, C2, C3, C4, C5, C6, C7; float Cb;

#define ISSUE_T(S, TI)                                                              \
  do {                                                                              \
    int t_ = w + (TI) * 8;                                                          \
    const bf16_t* np_ = W3q + t_ * 4096 + lane * 8;                                 \
    asm volatile("global_load_dwordx4 %0, %1, off" : "=v"(S##0) : "v"(np_));            \
    asm volatile("global_load_dwordx4 %0, %1, off" : "=v"(S##1) : "v"(np_ + 512));      \
    asm volatile("global_load_dwordx4 %0, %1, off" : "=v"(S##2) : "v"(np_ + 1024));     \
    asm volatile("global_load_dwordx4 %0, %1, off" : "=v"(S##3) : "v"(np_ + 1536));     \
    asm volatile("global_load_dwordx4 %0, %1, off" : "=v"(S##4) : "v"(np_ + 2048));     \
    asm volatile("global_load_dwordx4 %0, %1, off" : "=v"(S##5) : "v"(np_ + 2560));     \
    asm volatile("global_load_dwordx4 %0, %1, off" : "=v"(S##6) : "v"(np_ + 3072));     \
    asm volatile("global_load_dwordx4 %0, %1, off" : "=v"(S##7) : "v"(np_ + 3584));     \
    asm volatile("global_load_dword %0, %1, off"   : "=v"(S##b) : "v"(b3p + t_ * 16 + c)); \
  } while (0)

#define WAIT_N(N)                                          \
  do {                                                     \
    asm volatile("s_waitcnt vmcnt(" #N ")" ::: "memory");  \
    __builtin_amdgcn_sched_barrier(0);                     \
  } while (0)

#define COMP_T(S, TI)                                                      \
  do {                                                                     \
    f32x4 al0 = {S##b, S##b, S##b, S##b}, al1 = {0.f, 0.f, 0.f, 0.f};      \
    f32x4 ah0 = {S##b, S##b, S##b, S##b}, ah1 = {0.f, 0.f, 0.f, 0.f};      \
    al0 = MFMA16(aL0, S##0, al0); al1 = MFMA16(aL1, S##1, al1);            \
    ah0 = MFMA16(aH0, S##0, ah0); ah1 = MFMA16(aH1, S##1, ah1);            \
    al0 = MFMA16(aL2, S##2, al0); al1 = MFMA16(aL3, S##3, al1);            \
    ah0 = MFMA16(aH2, S##2, ah0); ah1 = MFMA16(aH3, S##3, ah1);            \
    al0 = MFMA16(aL4, S##4, al0); al1 = MFMA16(aL5, S##5, al1);            \
    ah0 = MFMA16(aH4, S##4, ah0); ah1 = MFMA16(aH5, S##5, ah1);            \
    al0 = MFMA16(aL6, S##6, al0); al1 = MFMA16(aL7, S##7, al1);            \
    ah0 = MFMA16(aH6, S##6, ah0); ah1 = MFMA16(aH7, S##7, ah1);            \
    f32x4 asL = al0 + al1;                                                 \
    f32x4 asH = ah0 + ah1;                                                 \
    int p_ = (w + (TI) * 8) * 16 + c;                                      \
    _Pragma("unroll")                                                      \
    for (int r_ = 0; r_ < 4; ++r_) {                                       \
      float vL = fast_tanh(asL[r_]);                                       \
      *(bf16_t*)(twL + r_ * SLOT + ((p_ * 2) ^ swzL)) = (bf16_t)vL;        \
      float vH = fast_tanh(asH[r_]);                                       \
      *(bf16_t*)(twH + r_ * SLOT + ((p_ * 2) ^ swzH)) = (bf16_t)vH;        \
    }                                                                      \
  } while (0)

    ISSUE_T(A, 0);
    ISSUE_T(B, 1);
#pragma unroll 1
    for (int k = 0; k < 6; ++k) {
      int t2 = 3 * k + 2;                              // always <= 17 (real)
      int t3 = (3 * k + 3 < 18) ? 3 * k + 3 : 17;      // clamped (redundant at tail)
      int t4 = (3 * k + 4 < 18) ? 3 * k + 4 : 17;
      ISSUE_T(C, t2);
      WAIT_N(18);
      COMP_T(A, 3 * k);
      ISSUE_T(A, t3);
      WAIT_N(18);
      COMP_T(B, 3 * k + 1);
      ISSUE_T(B, t4);
      WAIT_N(18);
      COMP_T(C, t2);
    }
    WAIT_N(0);   // drain redundant tail loads before regs get reused

#undef ISSUE_T
#undef WAIT_N
#undef COMP_T
  }
  __syncthreads();

  // ---- stage 4 (fused Gram): wave w -> batches 4w..4w+3, from LDS ----
#pragma unroll
  for (int bi = 0; bi < 4; ++bi) {
    int m = w * 4 + bi;
    char* slot = smem + m * SLOT;
    const int sw = ((m >> 2) & 7) << 4;

    bf16x8 f0, f1, f2, f3, f2b, f3b;
#pragma unroll
    for (int ti = 0; ti < 4; ++ti) {
      int j = ti * 16 + c;
      int Q = j >> 3, s = j & 7;
      int ro = 16 * (4 * Q * (Q + 1) + s * (Q + 1));
      bf16x8 fa = *(const bf16x8*)(slot + ((ro + g * 16) ^ sw));
      if (ti == 0) f0 = zsel(fa, g * 8 <= j);
      if (ti == 1) f1 = zsel(fa, g * 8 <= j);
      if (ti == 2) f2 = fa;
      if (ti == 3) f3 = fa;
      if (ti >= 2) {
        bf16x8 fb = *(const bf16x8*)(slot + ((ro + 64 + g * 16) ^ sw));
        fb = zsel(fb, 32 + g * 8 <= j);
        if (ti == 2) f2b = fb;
        else         f3b = fb;
      }
    }

    bf16x8 fA[4] = {f0, f1, f2, f3};
    f32x4 acc[4][4];
#pragma unroll
    for (int ti = 0; ti < 4; ++ti)
#pragma unroll
      for (int tj = 0; tj < 4; ++tj) {
        f32x4 z = {0.f, 0.f, 0.f, 0.f};
        acc[ti][tj] = MFMA16(fA[ti], fA[tj], z);
      }
    acc[2][2] = MFMA16(f2b, f2b, acc[2][2]);
    acc[2][3] = MFMA16(f2b, f3b, acc[2][3]);
    acc[3][2] = MFMA16(f3b, f2b, acc[3][2]);
    acc[3][3] = MFMA16(f3b, f3b, acc[3][3]);

    // slot is dead now -> reuse as 4KB y-staging; 1KB-contiguous NT stores
    float* yb = out + (size_t)(blk * 32 + m) * 4096;
#pragma unroll
    for (int ti = 0; ti < 4; ++ti) {
#pragma unroll
      for (int tj = 0; tj < 4; ++tj)
#pragma unroll
        for (int r = 0; r < 4; ++r)
          *(float*)(slot + (g * 4 + r) * 256 + (tj * 16 + c) * 4) = acc[ti][tj][r];
#pragma unroll
      for (int ii = 0; ii < 4; ++ii) {
        f32x4 v = *(const f32x4*)(slot + ii * 1024 + lane * 16);
        __builtin_nontemporal_store(v, (f32x4*)(yb + ti * 1024 + ii * 256 + lane * 4));
      }
    }
  }
}

extern "C" void kernel_launch(void* const* d_in, const int* in_sizes, int n_in,
                              void* d_out, int out_size, void* d_ws, size_t ws_size,
                              hipStream_t stream) {
  (void)in_sizes; (void)n_in; (void)out_size; (void)ws_size;
  const float* x  = (const float*)d_in[0];
  const float* W1 = (const float*)d_in[1];
  const float* b1 = (const float*)d_in[2];
  const float* W2 = (const float*)d_in[3];
  const float* b2 = (const float*)d_in[4];
  const float* W3 = (const float*)d_in[5];
  const float* b3 = (const float*)d_in[6];
  char* wsb = (char*)d_ws;   // needs 1,352,704 B
  float* out = (float*)d_out;

  prep_kernel<<<1317, 512, 0, stream>>>(W1, W2, W3, b3, wsb);

  hipFuncSetAttribute((const void*)hm_kernel,
                      hipFuncAttributeMaxDynamicSharedMemorySize, 163840);
  hm_kernel<<<1024, 512, 163840, stream>>>(x, b1, b2, wsb, out);
}

// Round 15
// 181.556 us; speedup vs baseline: 1.0534x; 1.0059x over previous
//
#include <hip/hip_runtime.h>

// HamiltonianMetric: y[b] = u^T u, u = scatter(tanh(MLP(x))).
// R15: persistent 8-round blocks (grid 256 = 1/CU), two alternating slot
// arenas. Round r: stages 1-3 (R12's proven 16-batch forms) fill arena[r&1];
// gram of set r-1 runs INSIDE round r's stage-3 tile loop, so its y-stores
// drain concurrently with the W3 L2-read stream (vmcnt FIFO: stores only add
// ops-after-load -> WAIT_N(9) guarantee preserved). Removes the serial
// write-only phase that R11-R14 paid every generation.

typedef __bf16 bf16_t;
typedef bf16_t bf16x8 __attribute__((ext_vector_type(8)));
typedef float  f32x4  __attribute__((ext_vector_type(4)));

#define MFMA16(a, b, c) __builtin_amdgcn_mfma_f32_16x16x32_bf16((a), (b), (c), 0, 0, 0)

constexpr int SLOT  = 4608;    // bytes per uT slot (XOR-swizzled)
constexpr int ARENA = 73728;   // 16 slots
constexpr int H2OFF = 147456;  // 2*ARENA; h2s at [147456,155648)

__device__ __forceinline__ float fast_tanh(float x) {
  float cx = fminf(fmaxf(x, -30.0f), 30.0f);
  float t  = __expf(2.0f * cx);
  return (t - 1.0f) * __builtin_amdgcn_rcpf(t + 1.0f);
}

__device__ __forceinline__ bf16x8 zsel(bf16x8 f, bool keep) {
  union { bf16x8 v; unsigned int u[4]; } x;
  x.v = f;
  unsigned m = keep ? 0xFFFFFFFFu : 0u;
#pragma unroll
  for (int p = 0; p < 4; ++p) x.u[p] &= m;
  return x.v;
}

// padded position p -> (j, k): row j has j+1 valid entries, padded to 8-mult
__device__ __forceinline__ void decode_p(int p, int& j, int& k) {
  int cc = p >> 3, e = p & 7;
  int b = 0;
  while (b < 7 && cc >= 4 * (b + 1) * (b + 2)) ++b;
  int rl  = b + 1;
  int rem = cc - 4 * b * (b + 1);
  j = 8 * b + rem / rl;
  k = (rem % rl) * 8 + e;
}

// ws: [0,16384) W1t[256n][64k] | [16384,81920) W2t[256n][256k] |
//     [81920,671744) W3q tile-major: [144 t][8 kk][64 lane][8 e]
//     byte 1343488: b3p[2304] f32 (permuted triangle bias, 0 in padding)
__global__ void prep_kernel(const float* __restrict__ W1, const float* __restrict__ W2,
                            const float* __restrict__ W3, const float* __restrict__ b3,
                            char* __restrict__ wsb) {
  int tid = blockIdx.x * 512 + threadIdx.x;
  bf16_t* ws = (bf16_t*)wsb;
  if (tid < 16384) {
    int n = tid >> 6, k = tid & 63;
    ws[tid] = (bf16_t)W1[k * 256 + n];
  } else if (tid < 81920) {
    int m = tid - 16384;
    int n = m >> 8, k = m & 255;
    ws[tid] = (bf16_t)W2[k * 256 + n];
  } else if (tid < 671744) {
    int m = tid - 81920;
    int t  = m >> 12;
    int r  = m & 4095;
    int kk = r >> 9;
    int g  = (r >> 7) & 3;
    int c  = (r >> 3) & 15;
    int e  = r & 7;
    int p  = t * 16 + c;          // triangle position
    int k  = kk * 32 + g * 8 + e; // H-dim column
    int j, kd;
    decode_p(p, j, kd);
    float v = 0.f;
    if (kd <= j) {
      int n_ref = (kd == j) ? j : (64 + kd * 63 - (kd * (kd - 1)) / 2 + j - kd - 1);
      v = W3[k * 2080 + n_ref];
    }
    ws[tid] = (bf16_t)v;
  } else if (tid < 674048) {
    int p = tid - 671744;
    int j, kd;
    decode_p(p, j, kd);
    float v = 0.f;
    if (kd <= j) {
      int n_ref = (kd == j) ? j : (64 + kd * 63 - (kd * (kd - 1)) / 2 + j - kd - 1);
      v = b3[n_ref];
    }
    ((float*)(wsb + 1343488))[p] = v;
  }
}

// gram one batch: read u frags from `slot` (sw-swizzled), 20 MFMAs, stage
// y stripes back into the (now dead) slot, 1KB-contiguous NT stores.
__device__ __forceinline__ void gram_store(char* slot, int sw, float* yb,
                                           int g, int c, int lane) {
  bf16x8 f0, f1, f2, f3, f2b, f3b;
#pragma unroll
  for (int ti = 0; ti < 4; ++ti) {
    int j = ti * 16 + c;
    int Q = j >> 3, s = j & 7;
    int ro = 16 * (4 * Q * (Q + 1) + s * (Q + 1));
    bf16x8 fa = *(const bf16x8*)(slot + ((ro + g * 16) ^ sw));
    if (ti == 0) f0 = zsel(fa, g * 8 <= j);
    if (ti == 1) f1 = zsel(fa, g * 8 <= j);
    if (ti == 2) f2 = fa;
    if (ti == 3) f3 = fa;
    if (ti >= 2) {
      bf16x8 fb = *(const bf16x8*)(slot + ((ro + 64 + g * 16) ^ sw));
      fb = zsel(fb, 32 + g * 8 <= j);
      if (ti == 2) f2b = fb;
      else         f3b = fb;
    }
  }

  bf16x8 fA[4] = {f0, f1, f2, f3};
  f32x4 acc[4][4];
#pragma unroll
  for (int ti = 0; ti < 4; ++ti)
#pragma unroll
    for (int tj = 0; tj < 4; ++tj) {
      f32x4 z = {0.f, 0.f, 0.f, 0.f};
      acc[ti][tj] = MFMA16(fA[ti], fA[tj], z);
    }
  acc[2][2] = MFMA16(f2b, f2b, acc[2][2]);
  acc[2][3] = MFMA16(f2b, f3b, acc[2][3]);
  acc[3][2] = MFMA16(f3b, f2b, acc[3][2]);
  acc[3][3] = MFMA16(f3b, f3b, acc[3][3]);

#pragma unroll
  for (int ti = 0; ti < 4; ++ti) {
#pragma unroll
    for (int tj = 0; tj < 4; ++tj)
#pragma unroll
      for (int r = 0; r < 4; ++r)
        *(float*)(slot + (g * 4 + r) * 256 + (tj * 16 + c) * 4) = acc[ti][tj][r];
#pragma unroll
    for (int ii = 0; ii < 4; ++ii) {
      f32x4 v = *(const f32x4*)(slot + ii * 1024 + lane * 16);
      __builtin_nontemporal_store(v, (f32x4*)(yb + ti * 1024 + ii * 256 + lane * 4));
    }
  }
}

// ------------- persistent kernel: 256 blocks x 8 rounds x 16 batches -------------
__global__ void __launch_bounds__(512, 2)
hm_kernel(const float* __restrict__ x, const float* __restrict__ b1,
          const float* __restrict__ b2, const char* __restrict__ wsb,
          float* __restrict__ out) {
  extern __shared__ char smem[];  // 155648 B
  const int tid  = threadIdx.x;
  const int w    = tid >> 6;    // wave 0..7
  const int lane = tid & 63;
  const int g    = lane >> 4;
  const int c    = lane & 15;
  const int blk  = blockIdx.x;

  const bf16_t* W1t = (const bf16_t*)wsb;
  const bf16_t* W2t = W1t + 16384;
  const bf16_t* W3q = W1t + 81920;
  const float*  b3p = (const float*)(wsb + 1343488);
  char* h2s = smem + H2OFF;  // [16][512B], swz

  // hoist biases (keeps mid-loop vmcnt stream free of compiler loads)
  float bias1[2], bias2[2];
#pragma unroll
  for (int ni = 0; ni < 2; ++ni) {
    int n = (w * 2 + ni) * 16 + c;
    bias1[ni] = b1[n];
    bias2[ni] = b2[n];
  }

#pragma unroll 1
  for (int r = 0; r < 8; ++r) {
    char* cur = smem + (r & 1) * ARENA;
    char* prv = smem + ((r & 1) ^ 1) * ARENA;
    char* xs  = cur;          // [16][128B], swz (scratch inside cur arena)
    char* h1s = cur + 4096;   // [16][512B], swz (scratch inside cur arena)

    // ---- load x: 16 rows x 64 f32 -> bf16 LDS ----
    if (tid < 256) {
      f32x4 v = *(const f32x4*)(x + ((size_t)blk * 128 + r * 16) * 64 + tid * 4);
      int row = tid >> 4, col = (tid & 15) * 4;
      union { bf16_t b[4]; unsigned long long u; } pk;
      pk.b[0] = (bf16_t)v[0]; pk.b[1] = (bf16_t)v[1];
      pk.b[2] = (bf16_t)v[2]; pk.b[3] = (bf16_t)v[3];
      *(unsigned long long*)(xs + ((row * 128 + col * 2) ^ ((row & 7) << 4))) = pk.u;
    }
    __syncthreads();

    // ---- stage 1: h1 = tanh(x @ W1 + b1) ----
    {
      bf16x8 a0 = *(const bf16x8*)(xs + ((c * 128 + g * 16) ^ ((c & 7) << 4)));
      bf16x8 a1 = *(const bf16x8*)(xs + ((c * 128 + 64 + g * 16) ^ ((c & 7) << 4)));
#pragma unroll
      for (int ni = 0; ni < 2; ++ni) {
        int n = (w * 2 + ni) * 16 + c;
        bf16x8 bw0 = *(const bf16x8*)(W1t + n * 64 + g * 8);
        bf16x8 bw1 = *(const bf16x8*)(W1t + n * 64 + 32 + g * 8);
        f32x4 acc = {0.f, 0.f, 0.f, 0.f};
        acc = MFMA16(a0, bw0, acc);
        acc = MFMA16(a1, bw1, acc);
#pragma unroll
        for (int rr = 0; rr < 4; ++rr) {
          int row = g * 4 + rr;
          float v = fast_tanh(acc[rr] + bias1[ni]);
          *(bf16_t*)(h1s + ((row * 512 + n * 2) ^ ((row & 7) << 4))) = (bf16_t)v;
        }
      }
    }
    __syncthreads();

    // ---- stage 2: h2 = tanh(h1 @ W2 + b2) ----
#pragma unroll
    for (int ni = 0; ni < 2; ++ni) {
      int n = (w * 2 + ni) * 16 + c;
      f32x4 acc0 = {0.f, 0.f, 0.f, 0.f}, acc1 = {0.f, 0.f, 0.f, 0.f};
#pragma unroll
      for (int kk = 0; kk < 8; kk += 2) {
        bf16x8 a0 = *(const bf16x8*)(h1s + ((c * 512 + kk * 64 + g * 16) ^ ((c & 7) << 4)));
        bf16x8 a1 = *(const bf16x8*)(h1s + ((c * 512 + (kk + 1) * 64 + g * 16) ^ ((c & 7) << 4)));
        bf16x8 bw0 = *(const bf16x8*)(W2t + n * 256 + kk * 32 + g * 8);
        bf16x8 bw1 = *(const bf16x8*)(W2t + n * 256 + (kk + 1) * 32 + g * 8);
        acc0 = MFMA16(a0, bw0, acc0);
        acc1 = MFMA16(a1, bw1, acc1);
      }
      f32x4 acc = acc0 + acc1;
#pragma unroll
      for (int rr = 0; rr < 4; ++rr) {
        int row = g * 4 + rr;
        float v = fast_tanh(acc[rr] + bias2[ni]);
        *(bf16_t*)(h2s + ((row * 512 + n * 2) ^ ((row & 7) << 4))) = (bf16_t)v;
      }
    }
    __syncthreads();

    // ---- stage 3 (fills cur arena) + interleaved gram(set r-1, prv arena) ----
    {
      bf16x8 a0 = *(const bf16x8*)(h2s + ((c * 512 + 0 * 64 + g * 16) ^ ((c & 7) << 4)));
      bf16x8 a1 = *(const bf16x8*)(h2s + ((c * 512 + 1 * 64 + g * 16) ^ ((c & 7) << 4)));
      bf16x8 a2 = *(const bf16x8*)(h2s + ((c * 512 + 2 * 64 + g * 16) ^ ((c & 7) << 4)));
      bf16x8 a3 = *(const bf16x8*)(h2s + ((c * 512 + 3 * 64 + g * 16) ^ ((c & 7) << 4)));
      bf16x8 a4 = *(const bf16x8*)(h2s + ((c * 512 + 4 * 64 + g * 16) ^ ((c & 7) << 4)));
      bf16x8 a5 = *(const bf16x8*)(h2s + ((c * 512 + 5 * 64 + g * 16) ^ ((c & 7) << 4)));
      bf16x8 a6 = *(const bf16x8*)(h2s + ((c * 512 + 6 * 64 + g * 16) ^ ((c & 7) << 4)));
      bf16x8 a7 = *(const bf16x8*)(h2s + ((c * 512 + 7 * 64 + g * 16) ^ ((c & 7) << 4)));

      char* tw = cur + (g * 4) * SLOT;   // slots g*4+r_
      const int swz = (g & 7) << 4;

      bf16x8 A0, A1, A2, A3, A4, A5, A6, A7; float Ab;
      bf16x8 B0, B1, B2, B3, B4, B5, B6, B7; float Bb;

#define ISSUE_T(S, TI)                                                              \
  do {                                                                              \
    int t_ = w + (TI) * 8;                                                          \
    const bf16_t* np_ = W3q + t_ * 4096 + lane * 8;                                 \
    asm volatile("global_load_dwordx4 %0, %1, off" : "=v"(S##0) : "v"(np_));            \
    asm volatile("global_load_dwordx4 %0, %1, off" : "=v"(S##1) : "v"(np_ + 512));      \
    asm volatile("global_load_dwordx4 %0, %1, off" : "=v"(S##2) : "v"(np_ + 1024));     \
    asm volatile("global_load_dwordx4 %0, %1, off" : "=v"(S##3) : "v"(np_ + 1536));     \
    asm volatile("global_load_dwordx4 %0, %1, off" : "=v"(S##4) : "v"(np_ + 2048));     \
    asm volatile("global_load_dwordx4 %0, %1, off" : "=v"(S##5) : "v"(np_ + 2560));     \
    asm volatile("global_load_dwordx4 %0, %1, off" : "=v"(S##6) : "v"(np_ + 3072));     \
    asm volatile("global_load_dwordx4 %0, %1, off" : "=v"(S##7) : "v"(np_ + 3584));     \
    asm volatile("global_load_dword %0, %1, off"   : "=v"(S##b) : "v"(b3p + t_ * 16 + c)); \
  } while (0)

#define WAIT_N(N)                                          \
  do {                                                     \
    asm volatile("s_waitcnt vmcnt(" #N ")" ::: "memory");  \
    __builtin_amdgcn_sched_barrier(0);                     \
  } while (0)

#define COMP_T(S, TI)                                                    \
  do {                                                                   \
    f32x4 acc0 = {S##b, S##b, S##b, S##b};                               \
    f32x4 acc1 = {0.f, 0.f, 0.f, 0.f};                                   \
    acc0 = MFMA16(a0, S##0, acc0); acc1 = MFMA16(a1, S##1, acc1);        \
    acc0 = MFMA16(a2, S##2, acc0); acc1 = MFMA16(a3, S##3, acc1);        \
    acc0 = MFMA16(a4, S##4, acc0); acc1 = MFMA16(a5, S##5, acc1);        \
    acc0 = MFMA16(a6, S##6, acc0); acc1 = MFMA16(a7, S##7, acc1);        \
    f32x4 accs = acc0 + acc1;                                            \
    int p_ = (w + (TI) * 8) * 16 + c;                                    \
    _Pragma("unroll")                                                    \
    for (int r_ = 0; r_ < 4; ++r_) {                                     \
      float v_ = fast_tanh(accs[r_]);                                    \
      *(bf16_t*)(tw + r_ * SLOT + ((p_ * 2) ^ swz)) = (bf16_t)v_;        \
    }                                                                    \
  } while (0)

      ISSUE_T(A, 0);
#pragma unroll 1
      for (int pr = 0; pr < 8; ++pr) {
        ISSUE_T(B, 2 * pr + 1);
        WAIT_N(9);
        COMP_T(A, 2 * pr);
        ISSUE_T(A, 2 * pr + 2);
        WAIT_N(9);
        COMP_T(B, 2 * pr + 1);
        // gram of previous set, stores drain under the remaining W3 reads
        if (r > 0 && (pr == 1 || pr == 5)) {
          int bi = (pr == 5);
          int m  = w * 2 + bi;
          gram_store(prv + m * SLOT, ((m >> 2) & 7) << 4,
                     out + ((size_t)blk * 128 + (r - 1) * 16 + m) * 4096,
                     g, c, lane);
        }
      }
      ISSUE_T(B, 17);
      WAIT_N(9);
      COMP_T(A, 16);
      WAIT_N(0);
      COMP_T(B, 17);

#undef ISSUE_T
#undef WAIT_N
#undef COMP_T
    }
    __syncthreads();
  }

  // ---- epilogue: gram the final set (round 7, arena 1) ----
#pragma unroll
  for (int bi = 0; bi < 2; ++bi) {
    int m = w * 2 + bi;
    gram_store(smem + ARENA + m * SLOT, ((m >> 2) & 7) << 4,
               out + ((size_t)blk * 128 + 7 * 16 + m) * 4096,
               g, c, lane);
  }
}

extern "C" void kernel_launch(void* const* d_in, const int* in_sizes, int n_in,
                              void* d_out, int out_size, void* d_ws, size_t ws_size,
                              hipStream_t stream) {
  (void)in_sizes; (void)n_in; (void)out_size; (void)ws_size;
  const float* x  = (const float*)d_in[0];
  const float* W1 = (const float*)d_in[1];
  const float* b1 = (const float*)d_in[2];
  const float* W2 = (const float*)d_in[3];
  const float* b2 = (const float*)d_in[4];
  const float* W3 = (const float*)d_in[5];
  const float* b3 = (const float*)d_in[6];
  char* wsb = (char*)d_ws;   // needs 1,352,704 B
  float* out = (float*)d_out;

  prep_kernel<<<1317, 512, 0, stream>>>(W1, W2, W3, b3, wsb);

  hipFuncSetAttribute((const void*)hm_kernel,
                      hipFuncAttributeMaxDynamicSharedMemorySize, 155648);
  hm_kernel<<<256, 512, 155648, stream>>>(x, b1, b2, wsb, out);
}